// Round 1
// 267.039 us; speedup vs baseline: 1.0734x; 1.0734x over previous
//
#include <hip/hip_runtime.h>
#include <hip/hip_bf16.h>

// ---------------- problem constants ----------------
#define B_TOTAL   32768
#define L_SITES   256
#define N_MID     254        // L-2 middle sites
#define HALF_PI_F 1.57079632679489662f
#define EPS_NORM  1e-8f

// ---------------- ws layout (float/dword slots) ----------------
// [WS_FRAG .. +520191]  B-fragment table: 254 steps x 8 frags x 64 lanes x 4 dwords
//                       frag q = h*4 + kh*2 + p  (h: n-half, kh: k-half/feature, p: 0=hi,1=lo)
// [WS_C0   .. +63]      core0 fp32  [f][32]
// [WS_CN   .. +639]     coreN fp32  [f][a][10]
// [WS_X    .. +8388607] xT fp32 [L][B]  (transposed)
// [WS_FLAG]             u32 flag: 1 = inputs are bf16, 0 = fp32
#define WS_FRAG 0
#define WS_C0   520192
#define WS_CN   520256
#define WS_X    520896
#define WS_FLAG 8909504

typedef short bf16x8 __attribute__((ext_vector_type(8)));
typedef float f32x4  __attribute__((ext_vector_type(4)));

__device__ __forceinline__ unsigned short f2bf(float f) {
    unsigned u = __builtin_bit_cast(unsigned, f);
    u += 0x7FFFu + ((u >> 16) & 1u);          // RNE
    return (unsigned short)(u >> 16);
}
__device__ __forceinline__ float bf2f(unsigned short h) {
    unsigned u = ((unsigned)h) << 16;
    return __builtin_bit_cast(float, u);
}
__device__ __forceinline__ bf16x8 asbf(uint4 u) {
    return __builtin_bit_cast(bf16x8, u);
}
// packed RNE f32x2 -> bf16x2 (lowers to v_cvt_pk_bf16_f32); memcpy because
// __hip_bfloat162 is not trivially copyable for __builtin_bit_cast
__device__ __forceinline__ unsigned pkbf2(float a, float b) {
    float2 p; p.x = a; p.y = b;
    __hip_bfloat162 h2 = __float22bfloat162_rn(p);
    unsigned u;
    __builtin_memcpy(&u, &h2, 4);
    return u;                                  // a in bits 0..15, b in 16..31
}
// split 8 fp32 into hi/lo bf16 fragments via packed cvt (same RNE math as the
// scalar split8 proven in rounds 2/7 — exonerated for correctness by r4-vs-r5/6)
__device__ __forceinline__ void split8(const float* v, bf16x8& hi, bf16x8& lo) {
    uint4 H, L;
    unsigned* hp = (unsigned*)&H;
    unsigned* lp = (unsigned*)&L;
    #pragma unroll
    for (int d = 0; d < 4; ++d) {
        float a = v[2 * d], b = v[2 * d + 1];
        unsigned hb = pkbf2(a, b);
        float h0 = __builtin_bit_cast(float, hb << 16);
        float h1 = __builtin_bit_cast(float, hb & 0xFFFF0000u);
        hp[d] = hb;
        lp[d] = pkbf2(a - h0, b - h1);         // exact residuals
    }
    hi = __builtin_bit_cast(bf16x8, H);
    lo = __builtin_bit_cast(bf16x8, L);
}
// per-wave input-dtype flag: bf16 pairs always have low16 < 0x4000
__device__ __forceinline__ bool detect_bf16(const unsigned* x_raw, int lane) {
    unsigned v = x_raw[lane];
    return __ballot((v & 0xFFFFu) >= 0x4000u) == 0ull;
}

// ---------------- fused aux kernel (round-5 structure, exonerated) ----------------
// blocks [0,2048)   : x transpose [B][L] -> xT [L][B] fp32
// blocks [2048,2556): B-fragment builder
// block  2556       : small cores -> fp32, + WS_FLAG write
__global__ __launch_bounds__(256)
void aux_all(const void* __restrict__ x_in, const void* __restrict__ c0_in,
             const void* __restrict__ am_in, const void* __restrict__ cn_in,
             float* __restrict__ ws) {
    const int lane = threadIdx.x & 63;
    const bool bf = detect_bf16((const unsigned*)x_in, lane);
    const int b = blockIdx.x;

    if (b < 2048) {
        __shared__ float tile[64][65];
        const int bb = (b & 511) * 64;
        const int ll = (b >> 9) * 64;
        #pragma unroll
        for (int k = 0; k < 16; ++k) {
            int idx = threadIdx.x + k * 256;
            int row = idx >> 6, col = idx & 63;
            size_t gi = (size_t)(bb + row) * L_SITES + ll + col;
            float v = bf ? bf2f(((const unsigned short*)x_in)[gi])
                         : ((const float*)x_in)[gi];
            tile[row][col] = v;
        }
        __syncthreads();
        #pragma unroll
        for (int k = 0; k < 16; ++k) {
            int idx = threadIdx.x + k * 256;
            int row = idx >> 6, col = idx & 63;
            ws[WS_X + (size_t)(ll + row) * B_TOTAL + bb + col] = tile[col][row];
        }
    } else if (b < 2556) {
        int i = (b - 2048) * 256 + threadIdx.x;
        if (i < N_MID * 8 * 64) {
            const int l  = i & 63;
            const int q  = (i >> 6) & 7;
            const int t  = i >> 9;
            const int h  = q >> 2;
            const int kh = (q >> 1) & 1;
            const int p  = q & 1;
            const int n  = h * 16 + (l & 15);
            const int kb = (l >> 4) * 8;
            unsigned dw[4];
            #pragma unroll
            for (int d = 0; d < 4; ++d) {
                unsigned e01[2];
                #pragma unroll
                for (int s = 0; s < 2; ++s) {
                    int a = kb + 2 * d + s;
                    size_t idx = ((size_t)(t * 2 + kh) * 32 + a) * 32 + n;
                    float v = bf ? bf2f(((const unsigned short*)am_in)[idx])
                                 : ((const float*)am_in)[idx];
                    unsigned short hi = f2bf(v);
                    e01[s] = (p == 0) ? hi : f2bf(v - bf2f(hi));
                }
                dw[d] = e01[0] | (e01[1] << 16);
            }
            uint4 o; o.x = dw[0]; o.y = dw[1]; o.z = dw[2]; o.w = dw[3];
            ((uint4*)ws)[(size_t)(t * 8 + q) * 64 + l] = o;
        }
    } else {
        for (int i = threadIdx.x; i < 640; i += 256) {
            if (i < 64)
                ws[WS_C0 + i] = bf ? bf2f(((const unsigned short*)c0_in)[i])
                                   : ((const float*)c0_in)[i];
            ws[WS_CN + i] = bf ? bf2f(((const unsigned short*)cn_in)[i])
                               : ((const float*)cn_in)[i];
        }
        if (threadIdx.x == 0)
            *(unsigned*)(ws + WS_FLAG) = bf ? 1u : 0u;
    }
}

// ---------------- main chain kernel ----------------
// Round-7-proven math: scaled stacks [ct*M ; st*M] @ [A0;A1] via two 3xBF16
// splits. THIS ROUND: latency attack (counters showed no pipe >51% busy at
// 2 waves/SIMD -> serial-chain latency-bound):
//   * 2x-unrolled main loop with ping-pong register sets: the 8 fragment
//     dwordx4 loads for step t+1 are issued during step t (zero-copy rotate),
//     so the L2 round-trip (~200-300 cyc) is off the critical path.
//   * xT load + __sincosf pipelined one step ahead (scale factors ready at
//     loop top).
//   * s_setprio(1) around the MFMA clusters (independent non-barriered waves).
// Numerics (split path, norm cadence, accumulation order) are bit-identical
// to the 284.8us baseline.
__global__ __launch_bounds__(256)
void mps_mfma(const float* __restrict__ ws, void* __restrict__ out) {
    __shared__ float T[4][528];                 // per-wave 16 rows x stride 33
    const int lane = threadIdx.x & 63;
    const int w    = threadIdx.x >> 6;
    const int r    = lane & 15;
    const int quad = lane >> 4;
    const int b0   = (blockIdx.x * 4 + w) * 16;
    const float* __restrict__ xT = ws + WS_X;
    const uint4* __restrict__ BF = (const uint4*)ws;   // WS_FRAG = 0
    float* __restrict__ Tw = &T[w][0];
    const int i = b0 + r;

    // ---- M0 in row-major k-slice order (not normalized, per reference) ----
    float mm[8];
    {
        float x0 = xT[i];
        float sn, cs; __sincosf(HALF_PI_F * x0, &sn, &cs);
        const float* c0 = ws + WS_C0;
        #pragma unroll
        for (int j = 0; j < 8; ++j) {
            int a = quad * 8 + j;
            mm[j] = cs * c0[a] + sn * c0[32 + a];
        }
    }

// one chain step: scale -> split -> 12 MFMA -> LDS transpose -> optional norm
#define DO_STEP(CT, ST, Q0, Q1, Q2, Q3, Q4, Q5, Q6, Q7, DONORM)                    \
    {                                                                              \
        float s0[8], s1[8];                                                        \
        _Pragma("unroll")                                                          \
        for (int j = 0; j < 8; ++j) { s0[j] = (CT) * mm[j]; s1[j] = (ST) * mm[j]; }\
        bf16x8 m0h, m0l, m1h, m1l;                                                 \
        split8(s0, m0h, m0l);                                                      \
        split8(s1, m1h, m1l);                                                      \
        const f32x4 z = {0.f, 0.f, 0.f, 0.f};                                      \
        __builtin_amdgcn_s_setprio(1);                                             \
        f32x4 a00 = __builtin_amdgcn_mfma_f32_16x16x32_bf16(m0h, asbf(Q0), z, 0, 0, 0);   \
        a00 = __builtin_amdgcn_mfma_f32_16x16x32_bf16(m0l, asbf(Q0), a00, 0, 0, 0);\
        a00 = __builtin_amdgcn_mfma_f32_16x16x32_bf16(m0h, asbf(Q1), a00, 0, 0, 0);\
        f32x4 a01 = __builtin_amdgcn_mfma_f32_16x16x32_bf16(m1h, asbf(Q2), z, 0, 0, 0);   \
        a01 = __builtin_amdgcn_mfma_f32_16x16x32_bf16(m1l, asbf(Q2), a01, 0, 0, 0);\
        a01 = __builtin_amdgcn_mfma_f32_16x16x32_bf16(m1h, asbf(Q3), a01, 0, 0, 0);\
        f32x4 a10 = __builtin_amdgcn_mfma_f32_16x16x32_bf16(m0h, asbf(Q4), z, 0, 0, 0);   \
        a10 = __builtin_amdgcn_mfma_f32_16x16x32_bf16(m0l, asbf(Q4), a10, 0, 0, 0);\
        a10 = __builtin_amdgcn_mfma_f32_16x16x32_bf16(m0h, asbf(Q5), a10, 0, 0, 0);\
        f32x4 a11 = __builtin_amdgcn_mfma_f32_16x16x32_bf16(m1h, asbf(Q6), z, 0, 0, 0);   \
        a11 = __builtin_amdgcn_mfma_f32_16x16x32_bf16(m1l, asbf(Q6), a11, 0, 0, 0);\
        a11 = __builtin_amdgcn_mfma_f32_16x16x32_bf16(m1h, asbf(Q7), a11, 0, 0, 0);\
        __builtin_amdgcn_s_setprio(0);                                             \
        f32x4 y0 = a00 + a01;    /* cols 0..15   (c = lane&15) */                  \
        f32x4 y1 = a10 + a11;    /* cols 16..31 */                                 \
        _Pragma("unroll")                                                          \
        for (int reg = 0; reg < 4; ++reg) {                                        \
            Tw[(quad * 4 + reg) * 33 + r]      = y0[reg];                          \
            Tw[(quad * 4 + reg) * 33 + 16 + r] = y1[reg];                          \
        }                                                                          \
        _Pragma("unroll")                                                          \
        for (int j = 0; j < 8; ++j) mm[j] = Tw[r * 33 + quad * 8 + j];             \
        if (DONORM) {                                                              \
            float ss = 0.f;                                                        \
            _Pragma("unroll")                                                      \
            for (int j = 0; j < 8; ++j) ss = fmaf(mm[j], mm[j], ss);               \
            ss += __shfl_xor(ss, 16);                                              \
            ss += __shfl_xor(ss, 32);                                              \
            float kk = 1.0f / (sqrtf(ss) + EPS_NORM);                              \
            _Pragma("unroll")                                                      \
            for (int j = 0; j < 8; ++j) mm[j] *= kk;                               \
        }                                                                          \
    }

    // ---- pipeline prologue ----
    // scale factors for step 0, x for step 1, fragments for step 0
    float ct0, st0;
    { float xc = xT[(size_t)B_TOTAL + i]; __sincosf(HALF_PI_F * xc, &st0, &ct0); }
    float x1 = xT[(size_t)2 * B_TOTAL + i];            // x of step 1

    const uint4* Ba = BF + lane;
    uint4 fa0 = Ba[0],   fa1 = Ba[64],  fa2 = Ba[128], fa3 = Ba[192];
    uint4 fa4 = Ba[256], fa5 = Ba[320], fa6 = Ba[384], fa7 = Ba[448];

    #pragma unroll 1
    for (int t = 0; t < N_MID; t += 2) {
        // ======== even step t: consumes (ct0,st0) + fa*; prefetch for t+1 ========
        const uint4* Bb = BF + (size_t)(t + 1) * 512 + lane;       // t+1 <= 253: valid
        uint4 fb0 = Bb[0],   fb1 = Bb[64],  fb2 = Bb[128], fb3 = Bb[192];
        uint4 fb4 = Bb[256], fb5 = Bb[320], fb6 = Bb[384], fb7 = Bb[448];
        float x2 = xT[(size_t)(t + 3) * B_TOTAL + i];              // x of step t+2 (t+3 <= 255)
        float ct1, st1; __sincosf(HALF_PI_F * x1, &st1, &ct1);     // factors for step t+1

        DO_STEP(ct0, st0, fa0, fa1, fa2, fa3, fa4, fa5, fa6, fa7, false)

        // ======== odd step t+1: consumes (ct1,st1) + fb*; prefetch for t+2 ========
        const uint4* Bc = BF + (size_t)(t + 2) * 512 + lane;       // t=252 -> step 254: in-ws garbage, never consumed
        fa0 = Bc[0];   fa1 = Bc[64];  fa2 = Bc[128]; fa3 = Bc[192];
        fa4 = Bc[256]; fa5 = Bc[320]; fa6 = Bc[384]; fa7 = Bc[448];
        int xr = t + 4; if (xr > 255) xr = 255;                    // clamp (t=252 -> 256)
        x1 = xT[(size_t)xr * B_TOTAL + i];                         // x of step t+3
        __sincosf(HALF_PI_F * x2, &st0, &ct0);                     // factors for step t+2

        DO_STEP(ct1, st1, fb0, fb1, fb2, fb3, fb4, fb5, fb6, fb7,
                (((t + 1) & 7) == 7) || (t + 1 == N_MID - 1))
    }
#undef DO_STEP

    // ---- readout: logits[r][c] = sum_a M[r][a]*(cN*KN0[a,c] + sN*KN1[a,c]) ----
    {
        float xN = xT[(size_t)(L_SITES - 1) * B_TOTAL + i];
        float sN, cN; __sincosf(HALF_PI_F * xN, &sN, &cN);
        const float* kn = ws + WS_CN;        // [f][a][10]
        float acc[10];
        #pragma unroll
        for (int c = 0; c < 10; ++c) acc[c] = 0.f;
        #pragma unroll
        for (int j = 0; j < 8; ++j) {
            int a = quad * 8 + j;
            float Ma = mm[j];
            #pragma unroll
            for (int c = 0; c < 10; ++c) {
                float fin = cN * kn[a * 10 + c] + sN * kn[320 + a * 10 + c];
                acc[c] = fmaf(Ma, fin, acc[c]);
            }
        }
        #pragma unroll
        for (int c = 0; c < 10; ++c) {
            acc[c] += __shfl_xor(acc[c], 16);
            acc[c] += __shfl_xor(acc[c], 32);
        }
        const unsigned bf = *(const unsigned*)(ws + WS_FLAG);
        if (quad == 0) {
            if (bf) {
                __hip_bfloat16* o = (__hip_bfloat16*)out;
                #pragma unroll
                for (int c = 0; c < 10; ++c)
                    o[(size_t)(b0 + r) * 10 + c] = __float2bfloat16(acc[c]);
            } else {
                float* o = (float*)out;
                #pragma unroll
                for (int c = 0; c < 10; ++c)
                    o[(size_t)(b0 + r) * 10 + c] = acc[c];
            }
        }
    }
}

// ---------------- launch ----------------
extern "C" void kernel_launch(void* const* d_in, const int* in_sizes, int n_in,
                              void* d_out, int out_size, void* d_ws, size_t ws_size,
                              hipStream_t stream) {
    float* ws = (float*)d_ws;
    aux_all<<<2557, 256, 0, stream>>>(d_in[0], d_in[1], d_in[2], d_in[3], ws);
    // 512 blocks x 4 waves x 16 samples = 32768 samples; 2048 waves = 2 waves/SIMD
    mps_mfma<<<512, 256, 0, stream>>>(ws, d_out);
}

// Round 2
// 244.988 us; speedup vs baseline: 1.1701x; 1.0900x over previous
//
#include <hip/hip_runtime.h>
#include <hip/hip_bf16.h>

// ---------------- problem constants ----------------
#define B_TOTAL   32768
#define L_SITES   256
#define N_MID     254        // L-2 middle sites
#define HALF_PI_F 1.57079632679489662f
#define EPS_NORM  1e-8f

// ---------------- ws layout (float/dword slots) ----------------
// [WS_FRAG .. +520191]  A-operand fragment table: 254 steps x 8 frags x 64 lanes x 4 dwords
//                       frag q = h*4 + kh*2 + p  (h: c-half, kh: feature, p: 0=hi,1=lo)
//                       NOTE (this round): contraction axis is PI-PERMUTED so the
//                       swapped-MFMA output feeds the next step with no transpose:
//                       k-slot (quad,j) holds a = (j<4 ? quad*4+j : 16+quad*4+j-4)
// [WS_C0   .. +63]      core0 fp32  [f][32]
// [WS_CN   .. +639]     coreN fp32  [f][a][10]
// [WS_X    .. +8388607] xT fp32 [L][B]  (transposed)
// [WS_FLAG]             u32 flag: 1 = inputs are bf16, 0 = fp32
#define WS_FRAG 0
#define WS_C0   520192
#define WS_CN   520256
#define WS_X    520896
#define WS_FLAG 8909504

typedef short bf16x8 __attribute__((ext_vector_type(8)));
typedef float f32x4  __attribute__((ext_vector_type(4)));

// pi-permutation of the contraction axis (k-slot -> actual a index)
__device__ __host__ __forceinline__ int pi_perm(int quad, int j) {
    return (j < 4) ? (quad * 4 + j) : (16 + quad * 4 + (j - 4));
}

__device__ __forceinline__ unsigned short f2bf(float f) {
    unsigned u = __builtin_bit_cast(unsigned, f);
    u += 0x7FFFu + ((u >> 16) & 1u);          // RNE
    return (unsigned short)(u >> 16);
}
__device__ __forceinline__ float bf2f(unsigned short h) {
    unsigned u = ((unsigned)h) << 16;
    return __builtin_bit_cast(float, u);
}
__device__ __forceinline__ bf16x8 asbf(uint4 u) {
    return __builtin_bit_cast(bf16x8, u);
}
// packed RNE f32x2 -> bf16x2 (lowers to v_cvt_pk_bf16_f32)
__device__ __forceinline__ unsigned pkbf2(float a, float b) {
    float2 p; p.x = a; p.y = b;
    __hip_bfloat162 h2 = __float22bfloat162_rn(p);
    unsigned u;
    __builtin_memcpy(&u, &h2, 4);
    return u;                                  // a in bits 0..15, b in 16..31
}
// split 8 fp32 into hi/lo bf16 fragments via packed cvt (RNE, proven)
__device__ __forceinline__ void split8(const float* v, bf16x8& hi, bf16x8& lo) {
    uint4 H, L;
    unsigned* hp = (unsigned*)&H;
    unsigned* lp = (unsigned*)&L;
    #pragma unroll
    for (int d = 0; d < 4; ++d) {
        float a = v[2 * d], b = v[2 * d + 1];
        unsigned hb = pkbf2(a, b);
        float h0 = __builtin_bit_cast(float, hb << 16);
        float h1 = __builtin_bit_cast(float, hb & 0xFFFF0000u);
        hp[d] = hb;
        lp[d] = pkbf2(a - h0, b - h1);         // exact residuals
    }
    hi = __builtin_bit_cast(bf16x8, H);
    lo = __builtin_bit_cast(bf16x8, L);
}
// per-wave input-dtype flag: bf16 pairs always have low16 < 0x4000
__device__ __forceinline__ bool detect_bf16(const unsigned* x_raw, int lane) {
    unsigned v = x_raw[lane];
    return __ballot((v & 0xFFFFu) >= 0x4000u) == 0ull;
}

// ---------------- fused aux kernel ----------------
// blocks [0,2048)   : x transpose [B][L] -> xT [L][B] fp32
// blocks [2048,2556): A-fragment builder (pi-permuted contraction axis)
// block  2556       : small cores -> fp32, + WS_FLAG write
__global__ __launch_bounds__(256)
void aux_all(const void* __restrict__ x_in, const void* __restrict__ c0_in,
             const void* __restrict__ am_in, const void* __restrict__ cn_in,
             float* __restrict__ ws) {
    const int lane = threadIdx.x & 63;
    const bool bf = detect_bf16((const unsigned*)x_in, lane);
    const int b = blockIdx.x;

    if (b < 2048) {
        __shared__ float tile[64][65];
        const int bb = (b & 511) * 64;
        const int ll = (b >> 9) * 64;
        #pragma unroll
        for (int k = 0; k < 16; ++k) {
            int idx = threadIdx.x + k * 256;
            int row = idx >> 6, col = idx & 63;
            size_t gi = (size_t)(bb + row) * L_SITES + ll + col;
            float v = bf ? bf2f(((const unsigned short*)x_in)[gi])
                         : ((const float*)x_in)[gi];
            tile[row][col] = v;
        }
        __syncthreads();
        #pragma unroll
        for (int k = 0; k < 16; ++k) {
            int idx = threadIdx.x + k * 256;
            int row = idx >> 6, col = idx & 63;
            ws[WS_X + (size_t)(ll + row) * B_TOTAL + bb + col] = tile[col][row];
        }
    } else if (b < 2556) {
        int i = (b - 2048) * 256 + threadIdx.x;
        if (i < N_MID * 8 * 64) {
            const int l  = i & 63;
            const int q  = (i >> 6) & 7;
            const int t  = i >> 9;
            const int h  = q >> 2;
            const int kh = (q >> 1) & 1;
            const int p  = q & 1;
            const int m  = h * 16 + (l & 15);      // output-c index (A-operand row)
            const int kb = (l >> 4) * 8;           // k-slot base for this lane's quad
            unsigned dw[4];
            #pragma unroll
            for (int d = 0; d < 4; ++d) {
                unsigned e01[2];
                #pragma unroll
                for (int s = 0; s < 2; ++s) {
                    int k  = kb + 2 * d + s;       // k-slot 0..31
                    int a  = pi_perm(k >> 3, k & 7); // PI-permuted contraction index
                    size_t idx = ((size_t)(t * 2 + kh) * 32 + a) * 32 + m;
                    float v = bf ? bf2f(((const unsigned short*)am_in)[idx])
                                 : ((const float*)am_in)[idx];
                    unsigned short hi = f2bf(v);
                    e01[s] = (p == 0) ? hi : f2bf(v - bf2f(hi));
                }
                dw[d] = e01[0] | (e01[1] << 16);
            }
            uint4 o; o.x = dw[0]; o.y = dw[1]; o.z = dw[2]; o.w = dw[3];
            ((uint4*)ws)[(size_t)(t * 8 + q) * 64 + l] = o;
        }
    } else {
        for (int i = threadIdx.x; i < 640; i += 256) {
            if (i < 64)
                ws[WS_C0 + i] = bf ? bf2f(((const unsigned short*)c0_in)[i])
                                   : ((const float*)c0_in)[i];
            ws[WS_CN + i] = bf ? bf2f(((const unsigned short*)cn_in)[i])
                               : ((const float*)cn_in)[i];
        }
        if (threadIdx.x == 0)
            *(unsigned*)(ws + WS_FLAG) = bf ? 1u : 0u;
    }
}

// ---------------- main chain kernel ----------------
// THIS ROUND: swapped-operand MFMA chain -> ZERO LDS on the critical path.
// Compute D_h[c][b] = sum_a A_f[a][h*16+c] * (scale*M)[b][a] with the table as
// the A-operand and scaled M as the B-operand. Because A- and B-fragment
// per-lane layouts are identical for 16x16x32 (row/col=lane&15, k=quad*8+j),
// and the table's contraction axis is pi-permuted, the C-layout output
// (col=lane&15=sample, row=quad*4+reg -> c=h*16+quad*4+reg = pi(quad,j))
// IS the next step's B-operand: the LDS transpose + its 120cyc ds_read latency
// + 1.67e7 bank-conflict cycles are gone. Same 12 MFMAs, same 3-split terms
// (T_hi*M_hi + T_lo*M_hi + T_hi*M_lo), same norm cadence.
// Keeps: round-1 ping-pong fragment prefetch, pipelined sincos, setprio.
__global__ __launch_bounds__(256)
void mps_mfma(const float* __restrict__ ws, void* __restrict__ out) {
    const int lane = threadIdx.x & 63;
    const int w    = threadIdx.x >> 6;
    const int r    = lane & 15;
    const int quad = lane >> 4;
    const int b0   = (blockIdx.x * 4 + w) * 16;
    const float* __restrict__ xT = ws + WS_X;
    const uint4* __restrict__ BF = (const uint4*)ws;   // WS_FRAG = 0
    const int i = b0 + r;

    // ---- M0 in pi-layout: mm[j] = M0[b=r][a=pi(quad,j)] ----
    float mm[8];
    {
        float x0 = xT[i];
        float sn, cs; __sincosf(HALF_PI_F * x0, &sn, &cs);
        const float* c0 = ws + WS_C0;
        #pragma unroll
        for (int j = 0; j < 8; ++j) {
            int a = pi_perm(quad, j);
            mm[j] = cs * c0[a] + sn * c0[32 + a];
        }
    }

// one chain step: scale -> split -> 12 MFMA (2 indep 6-chains) -> optional norm
#define DO_STEP(CT, ST, Q0, Q1, Q2, Q3, Q4, Q5, Q6, Q7, DONORM)                    \
    {                                                                              \
        float s0[8], s1[8];                                                        \
        _Pragma("unroll")                                                          \
        for (int j = 0; j < 8; ++j) { s0[j] = (CT) * mm[j]; s1[j] = (ST) * mm[j]; }\
        bf16x8 b0h, b0l, b1h, b1l;                                                 \
        split8(s0, b0h, b0l);                                                      \
        split8(s1, b1h, b1l);                                                      \
        const f32x4 z = {0.f, 0.f, 0.f, 0.f};                                      \
        __builtin_amdgcn_s_setprio(1);                                             \
        f32x4 a0 = __builtin_amdgcn_mfma_f32_16x16x32_bf16(asbf(Q0), b0h, z, 0, 0, 0);    \
        f32x4 a1 = __builtin_amdgcn_mfma_f32_16x16x32_bf16(asbf(Q4), b0h, z, 0, 0, 0);    \
        a0 = __builtin_amdgcn_mfma_f32_16x16x32_bf16(asbf(Q1), b0h, a0, 0, 0, 0);  \
        a1 = __builtin_amdgcn_mfma_f32_16x16x32_bf16(asbf(Q5), b0h, a1, 0, 0, 0);  \
        a0 = __builtin_amdgcn_mfma_f32_16x16x32_bf16(asbf(Q0), b0l, a0, 0, 0, 0);  \
        a1 = __builtin_amdgcn_mfma_f32_16x16x32_bf16(asbf(Q4), b0l, a1, 0, 0, 0);  \
        a0 = __builtin_amdgcn_mfma_f32_16x16x32_bf16(asbf(Q2), b1h, a0, 0, 0, 0);  \
        a1 = __builtin_amdgcn_mfma_f32_16x16x32_bf16(asbf(Q6), b1h, a1, 0, 0, 0);  \
        a0 = __builtin_amdgcn_mfma_f32_16x16x32_bf16(asbf(Q3), b1h, a0, 0, 0, 0);  \
        a1 = __builtin_amdgcn_mfma_f32_16x16x32_bf16(asbf(Q7), b1h, a1, 0, 0, 0);  \
        a0 = __builtin_amdgcn_mfma_f32_16x16x32_bf16(asbf(Q2), b1l, a0, 0, 0, 0);  \
        a1 = __builtin_amdgcn_mfma_f32_16x16x32_bf16(asbf(Q6), b1l, a1, 0, 0, 0);  \
        __builtin_amdgcn_s_setprio(0);                                             \
        mm[0] = a0[0]; mm[1] = a0[1]; mm[2] = a0[2]; mm[3] = a0[3];                \
        mm[4] = a1[0]; mm[5] = a1[1]; mm[6] = a1[2]; mm[7] = a1[3];                \
        if (DONORM) {                                                              \
            float ss = 0.f;                                                        \
            _Pragma("unroll")                                                      \
            for (int j = 0; j < 8; ++j) ss = fmaf(mm[j], mm[j], ss);               \
            ss += __shfl_xor(ss, 16);                                              \
            ss += __shfl_xor(ss, 32);                                              \
            float kk = 1.0f / (sqrtf(ss) + EPS_NORM);                              \
            _Pragma("unroll")                                                      \
            for (int j = 0; j < 8; ++j) mm[j] *= kk;                               \
        }                                                                          \
    }

    // ---- pipeline prologue ----
    float ct0, st0;
    { float xc = xT[(size_t)B_TOTAL + i]; __sincosf(HALF_PI_F * xc, &st0, &ct0); }
    float x1 = xT[(size_t)2 * B_TOTAL + i];            // x of step 1

    const uint4* Ba = BF + lane;
    uint4 fa0 = Ba[0],   fa1 = Ba[64],  fa2 = Ba[128], fa3 = Ba[192];
    uint4 fa4 = Ba[256], fa5 = Ba[320], fa6 = Ba[384], fa7 = Ba[448];

    #pragma unroll 1
    for (int t = 0; t < N_MID; t += 2) {
        // ======== even step t: consumes (ct0,st0) + fa*; prefetch for t+1 ========
        const uint4* Bb = BF + (size_t)(t + 1) * 512 + lane;       // t+1 <= 253: valid
        uint4 fb0 = Bb[0],   fb1 = Bb[64],  fb2 = Bb[128], fb3 = Bb[192];
        uint4 fb4 = Bb[256], fb5 = Bb[320], fb6 = Bb[384], fb7 = Bb[448];
        float x2 = xT[(size_t)(t + 3) * B_TOTAL + i];              // x of step t+2 (t+3 <= 255)
        float ct1, st1; __sincosf(HALF_PI_F * x1, &st1, &ct1);     // factors for step t+1

        DO_STEP(ct0, st0, fa0, fa1, fa2, fa3, fa4, fa5, fa6, fa7, false)

        // ======== odd step t+1: consumes (ct1,st1) + fb*; prefetch for t+2 ========
        const uint4* Bc = BF + (size_t)(t + 2) * 512 + lane;       // t=252 -> in-ws garbage, never consumed
        fa0 = Bc[0];   fa1 = Bc[64];  fa2 = Bc[128]; fa3 = Bc[192];
        fa4 = Bc[256]; fa5 = Bc[320]; fa6 = Bc[384]; fa7 = Bc[448];
        int xr = t + 4; if (xr > 255) xr = 255;                    // clamp (t=252 -> 256)
        x1 = xT[(size_t)xr * B_TOTAL + i];                         // x of step t+3
        __sincosf(HALF_PI_F * x2, &st0, &ct0);                     // factors for step t+2

        DO_STEP(ct1, st1, fb0, fb1, fb2, fb3, fb4, fb5, fb6, fb7,
                (((t + 1) & 7) == 7) || (t + 1 == N_MID - 1))
    }
#undef DO_STEP

    // ---- readout: logits[r][c] = sum_a M[r][a]*(cN*KN0[a,c] + sN*KN1[a,c]) ----
    {
        float xN = xT[(size_t)(L_SITES - 1) * B_TOTAL + i];
        float sN, cN; __sincosf(HALF_PI_F * xN, &sN, &cN);
        const float* kn = ws + WS_CN;        // [f][a][10]
        float acc[10];
        #pragma unroll
        for (int c = 0; c < 10; ++c) acc[c] = 0.f;
        #pragma unroll
        for (int j = 0; j < 8; ++j) {
            int a = pi_perm(quad, j);
            float Ma = mm[j];
            #pragma unroll
            for (int c = 0; c < 10; ++c) {
                float fin = cN * kn[a * 10 + c] + sN * kn[320 + a * 10 + c];
                acc[c] = fmaf(Ma, fin, acc[c]);
            }
        }
        #pragma unroll
        for (int c = 0; c < 10; ++c) {
            acc[c] += __shfl_xor(acc[c], 16);
            acc[c] += __shfl_xor(acc[c], 32);
        }
        const unsigned bf = *(const unsigned*)(ws + WS_FLAG);
        if (quad == 0) {
            if (bf) {
                __hip_bfloat16* o = (__hip_bfloat16*)out;
                #pragma unroll
                for (int c = 0; c < 10; ++c)
                    o[(size_t)(b0 + r) * 10 + c] = __float2bfloat16(acc[c]);
            } else {
                float* o = (float*)out;
                #pragma unroll
                for (int c = 0; c < 10; ++c)
                    o[(size_t)(b0 + r) * 10 + c] = acc[c];
            }
        }
    }
}

// ---------------- launch ----------------
extern "C" void kernel_launch(void* const* d_in, const int* in_sizes, int n_in,
                              void* d_out, int out_size, void* d_ws, size_t ws_size,
                              hipStream_t stream) {
    float* ws = (float*)d_ws;
    aux_all<<<2557, 256, 0, stream>>>(d_in[0], d_in[1], d_in[2], d_in[3], ws);
    // 512 blocks x 4 waves x 16 samples = 32768 samples; 2048 waves = 2 waves/SIMD
    mps_mfma<<<512, 256, 0, stream>>>(ws, d_out);
}